// Round 1
// baseline (101.127 us; speedup 1.0000x reference)
//
#include <hip/hip_runtime.h>
#include <math.h>

// spikeLN: s = OATN-quantize(x); y = LayerNorm_D(s) * weight + bias
// x: [B*S, D] f32, D = 4096. weight/bias: [D] f32. out: [B*S, D] f32.

#define LN_D      4096
#define LN_BLOCK  256
// each thread: 4 x float4 = 16 elements; 256 threads * 16 = 4096 = D

// Saturation constants: vmax * (1 - 2^-16), computed in double, cast to f32
// (matches Python-f64 constant folding in the reference).
#define SAT10  ((float)(10.0  * (1.0 - 1.0/65536.0)))
#define SAT500 ((float)(500.0 * (1.0 - 1.0/65536.0)))

__device__ __forceinline__ float oatn_f32(float xf) {
    // clip to [-500, 500]
    float xc = fminf(fmaxf(xf, -500.0f), 500.0f);
    float a  = fabsf(xc);
    // branch select: |x| < 10 -> vmax 10, else vmax 500
    bool small = (a < 10.0f);
    float vmax = small ? 10.0f  : 500.0f;
    float sat  = small ? SAT10  : SAT500;
    // q = floor(a / vmax * 65536) / 65536 * vmax   (exact op order of reference;
    // true IEEE division so floor boundaries bit-match numpy)
    float q = floorf(a / vmax * 65536.0f) * (1.0f / 65536.0f) * vmax;
    q = fminf(q, sat);
    // apply sign; q >= 0 and q == 0 when xc == 0, so sign(0)=0 case is benign
    return copysignf(q, xc);
}

__global__ __launch_bounds__(LN_BLOCK, 4)
void spikeln_kernel(const float* __restrict__ x,
                    const float* __restrict__ w,
                    const float* __restrict__ b,
                    float* __restrict__ out)
{
    const int row = blockIdx.x;
    const size_t base = (size_t)row * LN_D;
    const float4* __restrict__ x4 = reinterpret_cast<const float4*>(x + base);
    float4* __restrict__ y4       = reinterpret_cast<float4*>(out + base);
    const float4* __restrict__ w4 = reinterpret_cast<const float4*>(w);
    const float4* __restrict__ b4 = reinterpret_cast<const float4*>(b);

    const int tid  = threadIdx.x;
    const int lane = tid & 63;
    const int wid  = tid >> 6;

    float s[16];
    float psum = 0.0f;

    // Pass 1: load + quantize into registers, partial sum
    #pragma unroll
    for (int c = 0; c < 4; ++c) {
        float4 v = x4[tid + c * LN_BLOCK];
        float q0 = oatn_f32(v.x);
        float q1 = oatn_f32(v.y);
        float q2 = oatn_f32(v.z);
        float q3 = oatn_f32(v.w);
        s[c * 4 + 0] = q0;
        s[c * 4 + 1] = q1;
        s[c * 4 + 2] = q2;
        s[c * 4 + 3] = q3;
        psum += (q0 + q1) + (q2 + q3);
    }

    __shared__ float red[8];

    // block reduce: sum -> mean
    float t = psum;
    #pragma unroll
    for (int off = 32; off > 0; off >>= 1) t += __shfl_down(t, off);
    if (lane == 0) red[wid] = t;
    __syncthreads();
    const float mu = (red[0] + red[1] + red[2] + red[3]) * (1.0f / (float)LN_D);

    // Pass 2 (registers only): sum of squared deviations -> var
    float p2 = 0.0f;
    #pragma unroll
    for (int i = 0; i < 16; ++i) {
        float d = s[i] - mu;
        p2 += d * d;
    }
    t = p2;
    #pragma unroll
    for (int off = 32; off > 0; off >>= 1) t += __shfl_down(t, off);
    if (lane == 0) red[4 + wid] = t;
    __syncthreads();
    const float var = (red[4] + red[5] + red[6] + red[7]) * (1.0f / (float)LN_D);
    const float rstd = 1.0f / sqrtf(var + 1e-5f);

    // Pass 3: normalize, affine, store
    #pragma unroll
    for (int c = 0; c < 4; ++c) {
        const int idx = tid + c * LN_BLOCK;
        float4 wv = w4[idx];
        float4 bv = b4[idx];
        float4 o;
        o.x = (s[c * 4 + 0] - mu) * rstd * wv.x + bv.x;
        o.y = (s[c * 4 + 1] - mu) * rstd * wv.y + bv.y;
        o.z = (s[c * 4 + 2] - mu) * rstd * wv.z + bv.z;
        o.w = (s[c * 4 + 3] - mu) * rstd * wv.w + bv.w;
        y4[idx] = o;
    }
}

extern "C" void kernel_launch(void* const* d_in, const int* in_sizes, int n_in,
                              void* d_out, int out_size, void* d_ws, size_t ws_size,
                              hipStream_t stream) {
    const float* x = (const float*)d_in[0];
    const float* w = (const float*)d_in[1];
    const float* b = (const float*)d_in[2];
    float* out = (float*)d_out;

    const int nrows = in_sizes[0] / LN_D;  // B*S = 16384
    spikeln_kernel<<<nrows, LN_BLOCK, 0, stream>>>(x, w, b, out);
}

// Round 3
// 92.151 us; speedup vs baseline: 1.0974x; 1.0974x over previous
//
#include <hip/hip_runtime.h>
#include <math.h>

// spikeLN: s = OATN-quantize(x); y = LayerNorm_D(s) * weight + bias
// x: [B*S, D] f32, D = 4096. weight/bias: [D] f32. out: [B*S, D] f32.

#define LN_D      4096
#define LN_BLOCK  256
// each thread: 4 x vec4 = 16 elements; 256 threads * 16 = 4096 = D

// native clang vector (required by __builtin_nontemporal_*)
typedef float f32x4 __attribute__((ext_vector_type(4)));

// Saturation constants: vmax * (1 - 2^-16)
#define SAT10  ((float)(10.0  * (1.0 - 1.0/65536.0)))
#define SAT500 ((float)(500.0 * (1.0 - 1.0/65536.0)))

__device__ __forceinline__ float oatn_f32(float xf) {
    // clip to [-500, 500]
    float xc = fminf(fmaxf(xf, -500.0f), 500.0f);
    float a  = fabsf(xc);
    bool small = (a < 10.0f);
    // fold the divide into one multiply: floor(a/vmax*65536) == floor(a * (65536/vmax))
    // (constant rounded once; boundary shifts are <= 1 quant step, ~1e-3 post-LN)
    float mul   = small ? (65536.0f / 10.0f) : (65536.0f / 500.0f);
    float scale = small ? (10.0f / 65536.0f) : (500.0f / 65536.0f);  // both exact in f32
    float sat   = small ? SAT10 : SAT500;
    float q = floorf(a * mul) * scale;
    q = fminf(q, sat);
    return copysignf(q, xc);
}

__global__ __launch_bounds__(LN_BLOCK, 4)
void spikeln_kernel(const float* __restrict__ x,
                    const float* __restrict__ w,
                    const float* __restrict__ b,
                    float* __restrict__ out)
{
    const int row = blockIdx.x;
    const size_t base = (size_t)row * LN_D;
    const f32x4* __restrict__ x4 = reinterpret_cast<const f32x4*>(x + base);
    f32x4* __restrict__ y4       = reinterpret_cast<f32x4*>(out + base);
    const f32x4* __restrict__ w4 = reinterpret_cast<const f32x4*>(w);
    const f32x4* __restrict__ b4 = reinterpret_cast<const f32x4*>(b);

    const int tid  = threadIdx.x;
    const int lane = tid & 63;
    const int wid  = tid >> 6;

    float s[16];
    float psum = 0.0f;
    float psq  = 0.0f;

    // Pass 1: load (streaming) + quantize into registers, partial sum & sumsq
    #pragma unroll
    for (int c = 0; c < 4; ++c) {
        f32x4 v = __builtin_nontemporal_load(&x4[tid + c * LN_BLOCK]);
        float q0 = oatn_f32(v.x);
        float q1 = oatn_f32(v.y);
        float q2 = oatn_f32(v.z);
        float q3 = oatn_f32(v.w);
        s[c * 4 + 0] = q0;
        s[c * 4 + 1] = q1;
        s[c * 4 + 2] = q2;
        s[c * 4 + 3] = q3;
        psum += (q0 + q1) + (q2 + q3);
        psq = fmaf(q0, q0, psq);
        psq = fmaf(q1, q1, psq);
        psq = fmaf(q2, q2, psq);
        psq = fmaf(q3, q3, psq);
    }

    // Single reduction round: (sum, sumsq) together, one barrier.
    __shared__ float red[8];
    #pragma unroll
    for (int off = 32; off > 0; off >>= 1) {
        psum += __shfl_xor(psum, off);
        psq  += __shfl_xor(psq,  off);
    }
    if (lane == 0) { red[wid] = psum; red[4 + wid] = psq; }
    __syncthreads();

    const float sum = (red[0] + red[1]) + (red[2] + red[3]);
    const float sq  = (red[4] + red[5]) + (red[6] + red[7]);
    const float mu  = sum * (1.0f / (float)LN_D);
    float var = sq * (1.0f / (float)LN_D) - mu * mu;
    var = fmaxf(var, 0.0f);
    const float rstd = 1.0f / sqrtf(var + 1e-5f);

    // Pass 2: normalize, affine, streaming store
    #pragma unroll
    for (int c = 0; c < 4; ++c) {
        const int idx = tid + c * LN_BLOCK;
        f32x4 wv = w4[idx];
        f32x4 bv = b4[idx];
        f32x4 o;
        o.x = ((s[c * 4 + 0] - mu) * rstd) * wv.x + bv.x;
        o.y = ((s[c * 4 + 1] - mu) * rstd) * wv.y + bv.y;
        o.z = ((s[c * 4 + 2] - mu) * rstd) * wv.z + bv.z;
        o.w = ((s[c * 4 + 3] - mu) * rstd) * wv.w + bv.w;
        __builtin_nontemporal_store(o, &y4[idx]);
    }
}

extern "C" void kernel_launch(void* const* d_in, const int* in_sizes, int n_in,
                              void* d_out, int out_size, void* d_ws, size_t ws_size,
                              hipStream_t stream) {
    const float* x = (const float*)d_in[0];
    const float* w = (const float*)d_in[1];
    const float* b = (const float*)d_in[2];
    float* out = (float*)d_out;

    const int nrows = in_sizes[0] / LN_D;  // B*S = 16384
    spikeln_kernel<<<nrows, LN_BLOCK, 0, stream>>>(x, w, b, out);
}

// Round 4
// 91.232 us; speedup vs baseline: 1.1085x; 1.0101x over previous
//
#include <hip/hip_runtime.h>
#include <math.h>

// spikeLN: s = OATN-quantize(x); y = LayerNorm_D(s) * weight + bias
// x: [B*S, D] f32, D = 4096. weight/bias: [D] f32. out: [B*S, D] f32.

#define LN_D      4096
#define LN_BLOCK  512
// each thread: 2 x f32x4 = 8 elements; 512 threads * 8 = 4096 = D
// block=512, launch_bounds(512,8): forces VGPR<=64 -> 32 waves/CU (4 blocks/CU),
// 2x the occupancy of the 256-thread/s[16] version, smoothing the
// load->barrier->store phase boundary across resident blocks.

// native clang vector (required by __builtin_nontemporal_*)
typedef float f32x4 __attribute__((ext_vector_type(4)));

// Saturation constants: vmax * (1 - 2^-16)
#define SAT10  ((float)(10.0  * (1.0 - 1.0/65536.0)))
#define SAT500 ((float)(500.0 * (1.0 - 1.0/65536.0)))

__device__ __forceinline__ float oatn_f32(float xf) {
    // clip to [-500, 500]
    float xc = fminf(fmaxf(xf, -500.0f), 500.0f);
    float a  = fabsf(xc);
    bool small = (a < 10.0f);
    // divide-free: floor(a/vmax*65536) == floor(a * (65536/vmax))
    float mul   = small ? (65536.0f / 10.0f) : (65536.0f / 500.0f);
    float scale = small ? (10.0f / 65536.0f) : (500.0f / 65536.0f);  // exact in f32
    float sat   = small ? SAT10 : SAT500;
    float q = floorf(a * mul) * scale;
    q = fminf(q, sat);
    return copysignf(q, xc);
}

__global__ __launch_bounds__(LN_BLOCK, 8)
void spikeln_kernel(const float* __restrict__ x,
                    const float* __restrict__ w,
                    const float* __restrict__ b,
                    float* __restrict__ out)
{
    const int row = blockIdx.x;
    const size_t base = (size_t)row * LN_D;
    const f32x4* __restrict__ x4 = reinterpret_cast<const f32x4*>(x + base);
    f32x4* __restrict__ y4       = reinterpret_cast<f32x4*>(out + base);
    const f32x4* __restrict__ w4 = reinterpret_cast<const f32x4*>(w);
    const f32x4* __restrict__ b4 = reinterpret_cast<const f32x4*>(b);

    const int tid  = threadIdx.x;
    const int lane = tid & 63;
    const int wid  = tid >> 6;   // 8 waves

    float s[8];
    float psum = 0.0f;
    float psq  = 0.0f;

    // Pass 1: streaming load + quantize into registers, partial (sum, sumsq)
    #pragma unroll
    for (int c = 0; c < 2; ++c) {
        f32x4 v = __builtin_nontemporal_load(&x4[tid + c * LN_BLOCK]);
        float q0 = oatn_f32(v.x);
        float q1 = oatn_f32(v.y);
        float q2 = oatn_f32(v.z);
        float q3 = oatn_f32(v.w);
        s[c * 4 + 0] = q0;
        s[c * 4 + 1] = q1;
        s[c * 4 + 2] = q2;
        s[c * 4 + 3] = q3;
        psum += (q0 + q1) + (q2 + q3);
        psq = fmaf(q0, q0, psq);
        psq = fmaf(q1, q1, psq);
        psq = fmaf(q2, q2, psq);
        psq = fmaf(q3, q3, psq);
    }

    // Single reduction round: (sum, sumsq) together, one barrier.
    __shared__ float red[16];
    #pragma unroll
    for (int off = 32; off > 0; off >>= 1) {
        psum += __shfl_xor(psum, off);
        psq  += __shfl_xor(psq,  off);
    }
    if (lane == 0) { red[wid] = psum; red[8 + wid] = psq; }
    __syncthreads();

    float sum = 0.0f, sq = 0.0f;
    #pragma unroll
    for (int i = 0; i < 8; ++i) { sum += red[i]; sq += red[8 + i]; }
    const float mu  = sum * (1.0f / (float)LN_D);
    float var = sq * (1.0f / (float)LN_D) - mu * mu;
    var = fmaxf(var, 0.0f);
    const float rstd = 1.0f / sqrtf(var + 1e-5f);

    // Pass 2: normalize, affine, streaming store
    #pragma unroll
    for (int c = 0; c < 2; ++c) {
        const int idx = tid + c * LN_BLOCK;
        f32x4 wv = w4[idx];
        f32x4 bv = b4[idx];
        f32x4 o;
        o.x = ((s[c * 4 + 0] - mu) * rstd) * wv.x + bv.x;
        o.y = ((s[c * 4 + 1] - mu) * rstd) * wv.y + bv.y;
        o.z = ((s[c * 4 + 2] - mu) * rstd) * wv.z + bv.z;
        o.w = ((s[c * 4 + 3] - mu) * rstd) * wv.w + bv.w;
        __builtin_nontemporal_store(o, &y4[idx]);
    }
}

extern "C" void kernel_launch(void* const* d_in, const int* in_sizes, int n_in,
                              void* d_out, int out_size, void* d_ws, size_t ws_size,
                              hipStream_t stream) {
    const float* x = (const float*)d_in[0];
    const float* w = (const float*)d_in[1];
    const float* b = (const float*)d_in[2];
    float* out = (float*)d_out;

    const int nrows = in_sizes[0] / LN_D;  // B*S = 16384
    spikeln_kernel<<<nrows, LN_BLOCK, 0, stream>>>(x, w, b, out);
}